// Round 18
// baseline (229.367 us; speedup 1.0000x reference)
//
#include <hip/hip_runtime.h>
#include <hip/hip_bf16.h>
#include <math.h>

// T=4096, B=4, S=16 -> BS=64, F=64, CH=97 (16 B | 16 C | 1 A | 64 X), K=5.
// Output: (T, B, S) float32, flat index t*64 + bs.
//
// ROUND 18: r16-validated structure (199.6 us, absmax 0.5, bf16 Cm) +
// persistent-lite k_fwd: 512 blocks x 8 tiles.
//  - Weights hoisted ONCE per block (8x fewer weight loads).
//  - Software pipeline: tile i+1's x loads issued right after tile i's MFMA
//    barrier -> HBM latency hides under activation+Y_diag VALU phase
//    (r16 counters: k_fwd latency-bound, VALU 38% / MFMA 8% / HBM 5%;
//    4096 blocks each paid an exposed staging stall at start).
//  - Tail lesson (r3/r8/r16 cross-fit): ~20 us fixed overhead per launch;
//    launch count stays 3 (r15: cooperative launch rejected under graph
//    capture -> single-kernel is dead; r12: lookback chains 7us/link dead).

#define Tn 4096
#define BSn 64
#define Fn 64
#define CHn 97
#define CHP 112   // padded channels for MFMA (7 tiles of 16); ch97 = pass_w@k4
#define Kn 5
#define NCn 64
#define NBLK 512
#define TPB 8     // tiles per block

typedef __attribute__((ext_vector_type(8))) short bf16x8;
typedef __attribute__((ext_vector_type(4))) float f32x4;

static __device__ __forceinline__ unsigned short f2bf(float v) {
    __hip_bfloat16 b = __float2bfloat16(v);
    return *reinterpret_cast<unsigned short*>(&b);
}
static __device__ __forceinline__ float bf2f(unsigned short u) {
    unsigned v = ((unsigned)u) << 16;
    return __builtin_bit_cast(float, v);
}
static __device__ __forceinline__ float bflo(unsigned u) {  // low bf16 of u32
    return __builtin_bit_cast(float, u << 16);
}
static __device__ __forceinline__ float bfhi(unsigned u) {  // high bf16 of u32
    return __builtin_bit_cast(float, u & 0xffff0000u);
}

// ---------------- workspace layout (float units) ----------------
// end = OFF_WBL + 2560 = 9,592,832 fl = 38,371,328 B < validated envelope.
#define OFF_BD   0                      // (unused)
#define OFF_CM   (OFF_BD + 4194304)     // Cm as bf16
#define OFF_LAD  (OFF_CM + 4194304)     // (unused)
#define OFF_XQ   (OFF_LAD + 262144)     // (unused)
#define OFF_DL   (OFF_XQ + 262144)      // yp_ws
#define OFF_ACS  (OFF_DL + 262144)
#define OFF_SRED (OFF_ACS + 262144)
#define OFF_CSUM (OFF_SRED + 65536)
#define OFF_SNS  (OFF_CSUM + 4096)      // (unused)
#define OFF_WBH  (OFF_SNS + 65536)      // bf16 [k][112][64]
#define OFF_WBL  (OFF_WBH + 17920)      // bf16 lo-residual [k][16][64] (ch32..47)

// K0: weight prep. ch<97: conv_w; ch97,k=4: pass_w (Dx-as-GEMM row); else 0.
__global__ __launch_bounds__(256) void k_prep(const float* __restrict__ conv_w,
                                              const float* __restrict__ pass_w,
                                              unsigned short* __restrict__ wbh,
                                              unsigned short* __restrict__ wbl) {
    int idx = blockIdx.x * 256 + threadIdx.x;
    if (idx >= Kn * CHP * Fn) return;
    int f = idx & 63;
    int rest = idx >> 6;
    int ch = rest % CHP;
    int k = rest / CHP;
    float w = 0.f;
    if (ch < CHn) w = conv_w[(ch * Fn + f) * Kn + k];
    else if (ch == 97 && k == 4) w = pass_w[f];
    unsigned short hi = f2bf(w);
    wbh[idx] = hi;
    if (ch >= 32 && ch < 48)
        wbl[(k * 16 + (ch - 32)) * 64 + f] = f2bf(w - bf2f(hi));
}

// K1: fused conv + chunk + Y_diag (r16-validated body), 8 tiles per block,
// pipelined staging. Tile-per-wave: wv0: ct0(B)+ct4; wv1: ct1(C)+ct5;
// wv2: ct2+residual (A f32-exact); wv3: ct3+ct6 (ch96, Dx ch97).
__global__ __launch_bounds__(256) void k_fwd(
    const float* __restrict__ x, const unsigned short* __restrict__ wbh,
    const unsigned short* __restrict__ wbl,
    const float* __restrict__ conv_b, const float* __restrict__ pass_b,
    const float* __restrict__ red_w, const float* __restrict__ red_b,
    const float* __restrict__ dtp,
    unsigned short* __restrict__ Cm_h, float* __restrict__ Acs_ws,
    float* __restrict__ yp_ws, float* __restrict__ sred_ws,
    float* __restrict__ csum_ws) {
    const int b = blockIdx.x;
    const int tid = threadIdx.x;
    const int wv = tid >> 6, lane = tid & 63;
    const int qd = lane >> 4, n = lane & 15;

    // LDS pool: phase A: xsb[68*72] + xlo[68*72] bf16 (19584 B).
    // phase B (union): B0[64][20] | Ct[64][20] | pxl[4][64] | px2[4][64] |
    //   zsh[64] | dl[64]  (12800 B <= 19584).
    __shared__ alignas(16) unsigned char pool[19584];
    unsigned short* xsb = (unsigned short*)pool;
    unsigned short* xlo = (unsigned short*)(pool + 9792);
    float* B0  = (float*)pool;            // [64][20]
    float* Ct  = (float*)(pool + 5120);   // [64][20]
    float* pxl = (float*)(pool + 10240);  // [4][64]
    float* px2 = (float*)(pool + 11264);  // [4][64]
    float* zsh = (float*)(pool + 12288);  // [64]
    float* dl  = (float*)(pool + 12544);  // [64]

    // ---- weights hoisted ONCE per block (8x fewer loads than per-tile)
    const int tB = (wv == 3) ? 6 : wv + 4;               // wv2: unused
    const unsigned short* pBw = (wv == 2) ? wbl : wbh;
    const int sB = (wv == 2) ? 16 : CHP;
    const int cB = (wv == 2) ? 0 : 16 * tB;
    bf16x8 wA[10], wB[10];
#pragma unroll
    for (int s = 0; s < 10; ++s) {
        const int k = s >> 1, f0 = 32 * (s & 1) + qd * 8;
        wA[s] = *(const bf16x8*)&wbh[((k * CHP + 16 * wv + n) << 6) + f0];
        wB[s] = *(const bf16x8*)&pBw[((k * sB + cB + n) << 6) + f0];
    }

    const float dt = log1pf(expf(dtp[0])) + 0.01f;

    // ---- prologue: stage loads for tile 0
    float4 v[5];
    {
        const int t0 = b * TPB;
        const int bs = t0 & 63, ci = t0 >> 6;
#pragma unroll
        for (int it = 0; it < 5; ++it) {
            int idx = tid + it * 256;
            int tt = idx >> 4, fq = (idx & 15) * 4;
            int t = ci * 64 - 4 + tt;
            v[it] = (idx < 68 * 16 && t >= 0)
                        ? *(const float4*)&x[(t * 64 + bs) * 64 + fq]
                        : make_float4(0.f, 0.f, 0.f, 0.f);
        }
    }

    for (int it8 = 0; it8 < TPB; ++it8) {
        const int tt8 = b * TPB + it8;
        const int bs = tt8 & 63, ci = tt8 >> 6;

        // ---- convert staged v -> LDS (bf16 hi + lo residual)
#pragma unroll
        for (int it = 0; it < 5; ++it) {
            int idx = tid + it * 256;
            if (idx < 68 * 16) {
                int tt = idx >> 4, fq = (idx & 15) * 4;
                ushort4 h, lo;
                h.x = f2bf(v[it].x); lo.x = f2bf(v[it].x - bf2f(h.x));
                h.y = f2bf(v[it].y); lo.y = f2bf(v[it].y - bf2f(h.y));
                h.z = f2bf(v[it].z); lo.z = f2bf(v[it].z - bf2f(h.z));
                h.w = f2bf(v[it].w); lo.w = f2bf(v[it].w - bf2f(h.w));
                *(ushort4*)&xsb[tt * 72 + fq] = h;
                *(ushort4*)&xlo[tt * 72 + fq] = lo;
            }
        }
        __syncthreads();  // b1: stage done

        // ---- MFMA (validated)
        f32x4 accA[4], accB[4];
#pragma unroll
        for (int rg = 0; rg < 4; ++rg) {
            accA[rg] = (f32x4){0.f, 0.f, 0.f, 0.f};
            accB[rg] = (f32x4){0.f, 0.f, 0.f, 0.f};
        }
        if (wv == 2) {
#pragma unroll
            for (int s = 0; s < 10; ++s) {
                const int k = s >> 1, f0 = 32 * (s & 1) + qd * 8;
#pragma unroll
                for (int rg = 0; rg < 4; ++rg) {
                    bf16x8 av = *(const bf16x8*)&xsb[(16 * rg + n + k) * 72 + f0];
                    bf16x8 al = *(const bf16x8*)&xlo[(16 * rg + n + k) * 72 + f0];
                    accA[rg] = __builtin_amdgcn_mfma_f32_16x16x32_bf16(av, wA[s], accA[rg], 0, 0, 0);
                    accA[rg] = __builtin_amdgcn_mfma_f32_16x16x32_bf16(al, wA[s], accA[rg], 0, 0, 0);
                    accA[rg] = __builtin_amdgcn_mfma_f32_16x16x32_bf16(av, wB[s], accA[rg], 0, 0, 0);
                }
            }
        } else {
#pragma unroll
            for (int s = 0; s < 10; ++s) {
                const int k = s >> 1, f0 = 32 * (s & 1) + qd * 8;
#pragma unroll
                for (int rg = 0; rg < 4; ++rg) {
                    bf16x8 av = *(const bf16x8*)&xsb[(16 * rg + n + k) * 72 + f0];
                    accA[rg] = __builtin_amdgcn_mfma_f32_16x16x32_bf16(av, wA[s], accA[rg], 0, 0, 0);
                    accB[rg] = __builtin_amdgcn_mfma_f32_16x16x32_bf16(av, wB[s], accB[rg], 0, 0, 0);
                }
            }
        }
        __syncthreads();  // b2: MFMA done; xsb/xlo lifetime ends

        // ---- prefetch next tile's x (latency hides under phases below)
        if (it8 + 1 < TPB) {
            const int tn = tt8 + 1;
            const int bsN = tn & 63, ciN = tn >> 6;
#pragma unroll
            for (int it = 0; it < 5; ++it) {
                int idx = tid + it * 256;
                int tt = idx >> 4, fq = (idx & 15) * 4;
                int t = ciN * 64 - 4 + tt;
                v[it] = (idx < 68 * 16 && t >= 0)
                            ? *(const float4*)&x[(t * 64 + bsN) * 64 + fq]
                            : make_float4(0.f, 0.f, 0.f, 0.f);
            }
        }

        // ---- activation phase (validated; Cm stored bf16)
        const int cbase = (bs * 64 + ci) * 64;
        float px[4][4];
#pragma unroll
        for (int rg = 0; rg < 4; ++rg)
#pragma unroll
            for (int reg = 0; reg < 4; ++reg) px[rg][reg] = 0.f;

        if (wv == 0) {
            const float cb0 = conv_b[n];
            const float cb4 = conv_b[64 + n], rw4 = red_w[31 + n];
#pragma unroll
            for (int rg = 0; rg < 4; ++rg)
#pragma unroll
                for (int reg = 0; reg < 4; ++reg) {
                    int row = 16 * rg + 4 * qd + reg;
                    float z0 = accA[rg][reg] + cb0;
                    float a0 = z0 + 1.f / (1.f + __expf(-z0));
                    accA[rg][reg] = a0;          // keep for sred
                    B0[row * 20 + n] = a0;
                    float z4 = accB[rg][reg] + cb4;
                    px[rg][reg] = (z4 + 1.f / (1.f + __expf(-z4))) * rw4;
                }
        } else if (wv == 1) {
            const float cb1 = conv_b[16 + n];
            const float cb5 = conv_b[80 + n], rw5 = red_w[47 + n];
#pragma unroll
            for (int rg = 0; rg < 4; ++rg)
#pragma unroll
                for (int reg = 0; reg < 4; ++reg) {
                    int row = 16 * rg + 4 * qd + reg;
                    float z1 = accA[rg][reg] + cb1;
                    float a1 = z1 + 1.f / (1.f + __expf(-z1));
                    Ct[row * 20 + n] = a1;                    // f32 for Y_diag
                    Cm_h[(cbase + row) * 16 + n] = f2bf(a1);  // bf16 for Y_off
                    float z5 = accB[rg][reg] + cb5;
                    px[rg][reg] = (z5 + 1.f / (1.f + __expf(-z5))) * rw5;
                }
        } else if (wv == 2) {
            const float cb2 = conv_b[32 + n];
            const float rw2 = (n >= 1) ? red_w[n - 1] : 0.f;
#pragma unroll
            for (int rg = 0; rg < 4; ++rg)
#pragma unroll
                for (int reg = 0; reg < 4; ++reg) {
                    int row = 16 * rg + 4 * qd + reg;
                    if (n == 0) zsh[row] = accA[rg][reg];   // raw A acc
                    float z = accA[rg][reg] + cb2;
                    px[rg][reg] = (z + 1.f / (1.f + __expf(-z))) * rw2;
                }
        } else {
            const float cb3 = conv_b[48 + n], rw3 = red_w[15 + n];
            const float cb6 = conv_b[96], rw6 = red_w[63];
            const float pb = pass_b[0], rb = red_b[0];
#pragma unroll
            for (int rg = 0; rg < 4; ++rg)
#pragma unroll
                for (int reg = 0; reg < 4; ++reg) {
                    int row = 16 * rg + 4 * qd + reg;
                    float z3 = accA[rg][reg] + cb3;
                    px[rg][reg] = (z3 + 1.f / (1.f + __expf(-z3))) * rw3;
                    if (n == 0) {  // ch96 X channel
                        float z6 = accB[rg][reg] + cb6;
                        px[rg][reg] += (z6 + 1.f / (1.f + __expf(-z6))) * rw6;
                    }
                    if (n == 1) {  // ch97 = Dx (raw)
                        float Dx = accB[rg][reg] + pb;
                        float DL = (Dx >= 0.f) ? Dx : 0.01f * Dx;
                        dl[row] = DL + rb;
                    }
                }
        }
        // xq partials: reduce px over the 16 'n' lanes
#pragma unroll
        for (int m = 1; m < 16; m <<= 1)
#pragma unroll
            for (int rg = 0; rg < 4; ++rg)
#pragma unroll
                for (int reg = 0; reg < 4; ++reg)
                    px[rg][reg] += __shfl_xor(px[rg][reg], m, 64);
        if (n == 0)
#pragma unroll
            for (int rg = 0; rg < 4; ++rg)
#pragma unroll
                for (int reg = 0; reg < 4; ++reg)
                    pxl[wv * 64 + 16 * rg + 4 * qd + reg] = px[rg][reg];
        __syncthreads();  // b3: B0, Ct, pxl, zsh, dl ready

        // ---- per-chunk scan (replicated per wave, lane = chunk row l)
        const int l = lane;
        float zA = zsh[l] + conv_b[32];
        float aA = zA + 1.f / (1.f + __expf(-zA));
        float An = -fabsf(aA);
        float lAd = dt * An;
        float fac = (__expf(lAd) - 1.f) / (An + 1e-9f);
        float s = lAd;  // inclusive Kogge-Stone scan over 64 lanes
#pragma unroll
        for (int k = 1; k < 64; k <<= 1) {
            float t2 = __shfl_up(s, k, 64);
            if (l >= k) s += t2;
        }
        const float acs_l = s;
        const float tot = __shfl(s, 63, 64);
        float xq = pxl[0 * 64 + l] + pxl[1 * 64 + l] + pxl[2 * 64 + l] + pxl[3 * 64 + l];
        const float wd = fac * xq;                                // diag weight
        const float wsd = wd * __expf(fmaxf(tot - acs_l, -20.f)); // state weight
        if (wv == 3) {
            Acs_ws[bs * Tn + ci * 64 + l] = acs_l;
            if (l == 0) csum_ws[bs * 64 + ci] = tot;
        }

        // ---- sred from wv0's live a0 regs
        if (wv == 0) {
            float sp = 0.f;
#pragma unroll
            for (int rg = 0; rg < 4; ++rg)
#pragma unroll
                for (int reg = 0; reg < 4; ++reg)
                    sp += accA[rg][reg] * __shfl(wsd, 16 * rg + 4 * qd + reg, 64);
            sp += __shfl_xor(sp, 16, 64);
            sp += __shfl_xor(sp, 32, 64);
            if (l < 16) sred_ws[(bs * 64 + ci) * 16 + l] = sp;
        }

        // ---- Y_diag: wave wv covers m in [16wv, 16wv+16)
        const float4 cc0 = *(const float4*)&Ct[l * 20 + 0];
        const float4 cc1 = *(const float4*)&Ct[l * 20 + 4];
        const float4 cc2 = *(const float4*)&Ct[l * 20 + 8];
        const float4 cc3 = *(const float4*)&Ct[l * 20 + 12];
        float part = 0.f;
#pragma unroll
        for (int mm = 0; mm < 16; ++mm) {
            const int m = 16 * wv + mm;
            const float4 b0 = *(const float4*)&B0[m * 20 + 0];   // broadcast
            const float4 b1 = *(const float4*)&B0[m * 20 + 4];
            const float4 b2 = *(const float4*)&B0[m * 20 + 8];
            const float4 b3 = *(const float4*)&B0[m * 20 + 12];
            float g = cc0.x * b0.x + cc0.y * b0.y + cc0.z * b0.z + cc0.w * b0.w +
                      cc1.x * b1.x + cc1.y * b1.y + cc1.z * b1.z + cc1.w * b1.w +
                      cc2.x * b2.x + cc2.y * b2.y + cc2.z * b2.z + cc2.w * b2.w +
                      cc3.x * b3.x + cc3.y * b3.y + cc3.z * b3.z + cc3.w * b3.w;
            float am = __shfl(acs_l, m, 64);
            float wm = __shfl(wd, m, 64);
            float arg = (m <= l) ? fmaxf(acs_l - am, -20.f) : -20.f;
            part += __expf(arg) * g * wm;
        }
        px2[wv * 64 + l] = part;
        __syncthreads();  // b4: px2 ready

        if (wv == 0)
            yp_ws[bs * Tn + ci * 64 + l] =
                px2[0 * 64 + l] + px2[1 * 64 + l] + px2[2 * 64 + l] + px2[3 * 64 + l] + dl[l];
        __syncthreads();  // b5: protect phase-B LDS before next tile's restage
    }
}

// K2: fused inter-chunk scan + output (r16-validated, bf16 Cm read).
__global__ __launch_bounds__(256) void k_out(
    const unsigned short* __restrict__ Cm_h, const float* __restrict__ Acs_ws,
    const float* __restrict__ sred_ws, const float* __restrict__ csum_ws,
    const float* __restrict__ yp_ws, float* __restrict__ out) {
    const int bs = blockIdx.y;
    const int tid = threadIdx.x;
    const int wv = tid >> 6, l = tid & 63;
    const int ci = blockIdx.x * 4 + wv;
    __shared__ float sn[4][16];
    const int base = bs * Tn + ci * 64;

    // in-block affine scan (validated): lane = chunk id, wave wv handles
    // n = 4*wv .. 4*wv+3.
    const float dexp = __expf(csum_ws[bs * 64 + l]);  // <= 1
#pragma unroll
    for (int j = 0; j < 4; ++j) {
        const int n = 4 * wv + j;
        float s = sred_ws[(bs * 64 + l) * 16 + n];
        float d = dexp;
#pragma unroll
        for (int k = 1; k < 64; k <<= 1) {
            float dp = __shfl_up(d, k, 64);
            float sp = __shfl_up(s, k, 64);
            if (l >= k) {
                s = d * sp + s;  // compose on top of lower segment (old d!)
                d = d * dp;
            }
        }
        float se = __shfl_up(s, 1, 64);
        float sns = (l == 0) ? 0.f : se;
        if ((l >> 2) == blockIdx.x) sn[l & 3][n] = sns;
    }

    const unsigned short* crow = &Cm_h[((bs * 64 + ci) * 64 + l) * 16];
    uint4 ua = *(const uint4*)crow;        // bf16 c0..c7
    uint4 ub = *(const uint4*)(crow + 8);  // bf16 c8..c15
    float yp = yp_ws[base + l];
    float acl = Acs_ws[base + l];
    __syncthreads();

    const float* s = sn[wv];
    float go = bflo(ua.x) * s[0]  + bfhi(ua.x) * s[1] +
               bflo(ua.y) * s[2]  + bfhi(ua.y) * s[3] +
               bflo(ua.z) * s[4]  + bfhi(ua.z) * s[5] +
               bflo(ua.w) * s[6]  + bfhi(ua.w) * s[7] +
               bflo(ub.x) * s[8]  + bfhi(ub.x) * s[9] +
               bflo(ub.y) * s[10] + bfhi(ub.y) * s[11] +
               bflo(ub.z) * s[12] + bfhi(ub.z) * s[13] +
               bflo(ub.w) * s[14] + bfhi(ub.w) * s[15];
    out[(ci * 64 + l) * 64 + bs] = yp + __expf(acl) * go;
}

extern "C" void kernel_launch(void* const* d_in, const int* in_sizes, int n_in,
                              void* d_out, int out_size, void* d_ws,
                              size_t ws_size, hipStream_t stream) {
    const float* x = (const float*)d_in[0];
    const float* conv_w = (const float*)d_in[1];
    const float* conv_b = (const float*)d_in[2];
    const float* pass_w = (const float*)d_in[3];
    const float* pass_b = (const float*)d_in[4];
    const float* red_w = (const float*)d_in[5];
    const float* red_b = (const float*)d_in[6];
    const float* dtp = (const float*)d_in[7];
    float* out = (float*)d_out;
    float* W = (float*)d_ws;
    (void)in_sizes; (void)n_in; (void)out_size; (void)ws_size;

    unsigned short* Cm_h = (unsigned short*)(W + OFF_CM);
    float* yp_ws = W + OFF_DL;
    float* Acs_ws = W + OFF_ACS;
    float* sred_ws = W + OFF_SRED;
    float* csum_ws = W + OFF_CSUM;
    unsigned short* wbh = (unsigned short*)(W + OFF_WBH);
    unsigned short* wbl = (unsigned short*)(W + OFF_WBL);

    k_prep<<<dim3((Kn * CHP * Fn + 255) / 256), dim3(256), 0, stream>>>(
        conv_w, pass_w, wbh, wbl);
    k_fwd<<<dim3(NBLK), dim3(256), 0, stream>>>(
        x, wbh, wbl, conv_b, pass_b, red_w, red_b, dtp,
        Cm_h, Acs_ws, yp_ws, sred_ws, csum_ws);
    k_out<<<dim3(NCn / 4, BSn), dim3(256), 0, stream>>>(
        Cm_h, Acs_ws, sred_ws, csum_ws, yp_ws, out);
}

// Round 21
// 170.178 us; speedup vs baseline: 1.3478x; 1.3478x over previous
//
#include <hip/hip_runtime.h>
#include <hip/hip_bf16.h>
#include <math.h>

// T=4096, B=4, S=16 -> BS=64, F=64, CH=97 (16 B | 16 C | 1 A | 64 X), K=5.
// Output: (T, B, S) float32, flat index t*64 + bs.
//
// ROUND 19: r16-validated structure (199.6 us) + Y_diag Gram via MFMA.
//  - r18 lesson: persistent-lite prefetch REGRESSED (VGPR 100->200, occ
//    21->11%): k_fwd hides latency via cross-block TLP; keep 4096 blocks.
//  - Y_diag was the dominant VALU phase (~350 ops/lane: 16x 16-wide f32
//    dots + 32 shfl + LDS cross-wave reduce). Now: G = C*B^T (64x64x16)
//    via 4 MFMAs/wave (K=16 padded to 32, zero qd>=2 fragments; same
//    operand layout as the validated conv MFMAs). Each wave owns complete
//    l-rows -> px2 cross-wave reduce deleted. exp count unchanged.
//  - C/B stored bf16 in LDS (Cb16/Bb16) by the activation phase; Y_diag
//    numerics go f32->bf16 (~0.4% rel on that term; absmax 0.5 -> ~0.8
//    expected, threshold 1.7).

#define Tn 4096
#define BSn 64
#define Fn 64
#define CHn 97
#define CHP 112   // padded channels for MFMA (7 tiles of 16); ch97 = pass_w@k4
#define Kn 5
#define NCn 64

typedef __attribute__((ext_vector_type(8))) short bf16x8;
typedef __attribute__((ext_vector_type(4))) float f32x4;

static __device__ __forceinline__ unsigned short f2bf(float v) {
    __hip_bfloat16 b = __float2bfloat16(v);
    return *reinterpret_cast<unsigned short*>(&b);
}
static __device__ __forceinline__ float bf2f(unsigned short u) {
    unsigned v = ((unsigned)u) << 16;
    return __builtin_bit_cast(float, v);
}
static __device__ __forceinline__ float bflo(unsigned u) {  // low bf16 of u32
    return __builtin_bit_cast(float, u << 16);
}
static __device__ __forceinline__ float bfhi(unsigned u) {  // high bf16 of u32
    return __builtin_bit_cast(float, u & 0xffff0000u);
}

// ---------------- workspace layout (float units) ----------------
// end = OFF_WBL + 2560 = 9,592,832 fl = 38,371,328 B < validated envelope.
#define OFF_BD   0                      // (unused)
#define OFF_CM   (OFF_BD + 4194304)     // Cm as bf16
#define OFF_LAD  (OFF_CM + 4194304)     // (unused)
#define OFF_XQ   (OFF_LAD + 262144)     // (unused)
#define OFF_DL   (OFF_XQ + 262144)      // yp_ws
#define OFF_ACS  (OFF_DL + 262144)
#define OFF_SRED (OFF_ACS + 262144)
#define OFF_CSUM (OFF_SRED + 65536)
#define OFF_SNS  (OFF_CSUM + 4096)      // (unused)
#define OFF_WBH  (OFF_SNS + 65536)      // bf16 [k][112][64]
#define OFF_WBL  (OFF_WBH + 17920)      // bf16 lo-residual [k][16][64] (ch32..47)

// K0: weight prep. ch<97: conv_w; ch97,k=4: pass_w (Dx-as-GEMM row); else 0.
__global__ __launch_bounds__(256) void k_prep(const float* __restrict__ conv_w,
                                              const float* __restrict__ pass_w,
                                              unsigned short* __restrict__ wbh,
                                              unsigned short* __restrict__ wbl) {
    int idx = blockIdx.x * 256 + threadIdx.x;
    if (idx >= Kn * CHP * Fn) return;
    int f = idx & 63;
    int rest = idx >> 6;
    int ch = rest % CHP;
    int k = rest / CHP;
    float w = 0.f;
    if (ch < CHn) w = conv_w[(ch * Fn + f) * Kn + k];
    else if (ch == 97 && k == 4) w = pass_w[f];
    unsigned short hi = f2bf(w);
    wbh[idx] = hi;
    if (ch >= 32 && ch < 48)
        wbl[(k * 16 + (ch - 32)) * 64 + f] = f2bf(w - bf2f(hi));
}

// K1: fused conv + chunk + Y_diag (Gram-MFMA). One block = one (ci,bs) tile.
// Tile-per-wave: wv0: ct0(B)+ct4; wv1: ct1(C)+ct5; wv2: ct2+residual
// (A f32-exact); wv3: ct3+ct6 (ch96, Dx ch97).
__global__ __launch_bounds__(256) void k_fwd(
    const float* __restrict__ x, const unsigned short* __restrict__ wbh,
    const unsigned short* __restrict__ wbl,
    const float* __restrict__ conv_b, const float* __restrict__ pass_b,
    const float* __restrict__ red_w, const float* __restrict__ red_b,
    const float* __restrict__ dtp,
    unsigned short* __restrict__ Cm_h, float* __restrict__ Acs_ws,
    float* __restrict__ yp_ws, float* __restrict__ sred_ws,
    float* __restrict__ csum_ws) {
    const int wgid = blockIdx.x;
    const int seq = wgid >> 3;
    const int bs = seq & 63;
    const int ci = ((seq >> 6) << 3) | (wgid & 7);
    const int tid = threadIdx.x;
    const int wv = tid >> 6, lane = tid & 63;
    const int qd = lane >> 4, n = lane & 15;

    // LDS pool: phase A: xsb[68*72] + xlo[68*72] bf16 (19584 B).
    // phase B (union, 6144 B): Bb16[64][16] u16 | Cb16[64][16] u16 |
    //   pxl[4][64] f32 | zsh[64] | dl[64] | acs_s[64] | wd_s[64]
    __shared__ alignas(16) unsigned char pool[19584];
    unsigned short* xsb = (unsigned short*)pool;
    unsigned short* xlo = (unsigned short*)(pool + 9792);
    unsigned short* Bb16 = (unsigned short*)pool;           // [64][16]
    unsigned short* Cb16 = (unsigned short*)(pool + 2048);  // [64][16]
    float* pxl  = (float*)(pool + 4096);   // [4][64]
    float* zsh  = (float*)(pool + 5120);   // [64]
    float* dl   = (float*)(pool + 5376);   // [64]
    float* acs_s = (float*)(pool + 5632);  // [64]
    float* wd_s  = (float*)(pool + 5888);  // [64]

    // ---- hoisted weight loads (validated): 20 bf16x8/lane, issued FIRST
    const int tB = (wv == 3) ? 6 : wv + 4;               // wv2: unused
    const unsigned short* pBw = (wv == 2) ? wbl : wbh;
    const int sB = (wv == 2) ? 16 : CHP;
    const int cB = (wv == 2) ? 0 : 16 * tB;
    bf16x8 wA[10], wB[10];
#pragma unroll
    for (int s = 0; s < 10; ++s) {
        const int k = s >> 1, f0 = 32 * (s & 1) + qd * 8;
        wA[s] = *(const bf16x8*)&wbh[((k * CHP + 16 * wv + n) << 6) + f0];
        wB[s] = *(const bf16x8*)&pBw[((k * sB + cB + n) << 6) + f0];
    }

    // ---- batched x staging
    float4 v[5];
#pragma unroll
    for (int it = 0; it < 5; ++it) {
        int idx = tid + it * 256;
        int tt = idx >> 4, fq = (idx & 15) * 4;
        int t = ci * 64 - 4 + tt;
        v[it] = (idx < 68 * 16 && t >= 0)
                    ? *(const float4*)&x[(t * 64 + bs) * 64 + fq]
                    : make_float4(0.f, 0.f, 0.f, 0.f);
    }
#pragma unroll
    for (int it = 0; it < 5; ++it) {
        int idx = tid + it * 256;
        if (idx < 68 * 16) {
            int tt = idx >> 4, fq = (idx & 15) * 4;
            ushort4 h, lo;
            h.x = f2bf(v[it].x); lo.x = f2bf(v[it].x - bf2f(h.x));
            h.y = f2bf(v[it].y); lo.y = f2bf(v[it].y - bf2f(h.y));
            h.z = f2bf(v[it].z); lo.z = f2bf(v[it].z - bf2f(h.z));
            h.w = f2bf(v[it].w); lo.w = f2bf(v[it].w - bf2f(h.w));
            *(ushort4*)&xsb[tt * 72 + fq] = h;
            *(ushort4*)&xlo[tt * 72 + fq] = lo;
        }
    }
    __syncthreads();  // b1: stage done (drains hoisted weight loads too)

    // ---- MFMA conv (validated)
    f32x4 accA[4], accB[4];
#pragma unroll
    for (int rg = 0; rg < 4; ++rg) {
        accA[rg] = (f32x4){0.f, 0.f, 0.f, 0.f};
        accB[rg] = (f32x4){0.f, 0.f, 0.f, 0.f};
    }
    if (wv == 2) {
#pragma unroll
        for (int s = 0; s < 10; ++s) {
            const int k = s >> 1, f0 = 32 * (s & 1) + qd * 8;
#pragma unroll
            for (int rg = 0; rg < 4; ++rg) {
                bf16x8 av = *(const bf16x8*)&xsb[(16 * rg + n + k) * 72 + f0];
                bf16x8 al = *(const bf16x8*)&xlo[(16 * rg + n + k) * 72 + f0];
                accA[rg] = __builtin_amdgcn_mfma_f32_16x16x32_bf16(av, wA[s], accA[rg], 0, 0, 0);
                accA[rg] = __builtin_amdgcn_mfma_f32_16x16x32_bf16(al, wA[s], accA[rg], 0, 0, 0);
                accA[rg] = __builtin_amdgcn_mfma_f32_16x16x32_bf16(av, wB[s], accA[rg], 0, 0, 0);
            }
        }
    } else {
#pragma unroll
        for (int s = 0; s < 10; ++s) {
            const int k = s >> 1, f0 = 32 * (s & 1) + qd * 8;
#pragma unroll
            for (int rg = 0; rg < 4; ++rg) {
                bf16x8 av = *(const bf16x8*)&xsb[(16 * rg + n + k) * 72 + f0];
                accA[rg] = __builtin_amdgcn_mfma_f32_16x16x32_bf16(av, wA[s], accA[rg], 0, 0, 0);
                accB[rg] = __builtin_amdgcn_mfma_f32_16x16x32_bf16(av, wB[s], accB[rg], 0, 0, 0);
            }
        }
    }
    __syncthreads();  // b2: MFMA done; xsb/xlo lifetime ends (union -> phase B)

    // ---- activation phase (validated math; B/C now bf16 into LDS)
    const int cbase = (bs * 64 + ci) * 64;
    float px[4][4];
#pragma unroll
    for (int rg = 0; rg < 4; ++rg)
#pragma unroll
        for (int reg = 0; reg < 4; ++reg) px[rg][reg] = 0.f;

    if (wv == 0) {
        const float cb0 = conv_b[n];
        const float cb4 = conv_b[64 + n], rw4 = red_w[31 + n];
#pragma unroll
        for (int rg = 0; rg < 4; ++rg)
#pragma unroll
            for (int reg = 0; reg < 4; ++reg) {
                int row = 16 * rg + 4 * qd + reg;
                float z0 = accA[rg][reg] + cb0;
                float a0 = z0 + 1.f / (1.f + __expf(-z0));
                accA[rg][reg] = a0;          // keep for sred
                Bb16[row * 16 + n] = f2bf(a0);
                float z4 = accB[rg][reg] + cb4;
                px[rg][reg] = (z4 + 1.f / (1.f + __expf(-z4))) * rw4;
            }
    } else if (wv == 1) {
        const float cb1 = conv_b[16 + n];
        const float cb5 = conv_b[80 + n], rw5 = red_w[47 + n];
#pragma unroll
        for (int rg = 0; rg < 4; ++rg)
#pragma unroll
            for (int reg = 0; reg < 4; ++reg) {
                int row = 16 * rg + 4 * qd + reg;
                float z1 = accA[rg][reg] + cb1;
                float a1 = z1 + 1.f / (1.f + __expf(-z1));
                unsigned short h = f2bf(a1);
                Cb16[row * 16 + n] = h;            // bf16 for Gram MFMA
                Cm_h[(cbase + row) * 16 + n] = h;  // bf16 for Y_off (k_out)
                float z5 = accB[rg][reg] + cb5;
                px[rg][reg] = (z5 + 1.f / (1.f + __expf(-z5))) * rw5;
            }
    } else if (wv == 2) {
        const float cb2 = conv_b[32 + n];
        const float rw2 = (n >= 1) ? red_w[n - 1] : 0.f;
#pragma unroll
        for (int rg = 0; rg < 4; ++rg)
#pragma unroll
            for (int reg = 0; reg < 4; ++reg) {
                int row = 16 * rg + 4 * qd + reg;
                if (n == 0) zsh[row] = accA[rg][reg];   // raw A acc
                float z = accA[rg][reg] + cb2;
                px[rg][reg] = (z + 1.f / (1.f + __expf(-z))) * rw2;
            }
    } else {
        const float cb3 = conv_b[48 + n], rw3 = red_w[15 + n];
        const float cb6 = conv_b[96], rw6 = red_w[63];
        const float pb = pass_b[0], rb = red_b[0];
#pragma unroll
        for (int rg = 0; rg < 4; ++rg)
#pragma unroll
            for (int reg = 0; reg < 4; ++reg) {
                int row = 16 * rg + 4 * qd + reg;
                float z3 = accA[rg][reg] + cb3;
                px[rg][reg] = (z3 + 1.f / (1.f + __expf(-z3))) * rw3;
                if (n == 0) {  // ch96 X channel
                    float z6 = accB[rg][reg] + cb6;
                    px[rg][reg] += (z6 + 1.f / (1.f + __expf(-z6))) * rw6;
                }
                if (n == 1) {  // ch97 = Dx (raw)
                    float Dx = accB[rg][reg] + pb;
                    float DL = (Dx >= 0.f) ? Dx : 0.01f * Dx;
                    dl[row] = DL + rb;
                }
            }
    }
    // xq partials: reduce px over the 16 'n' lanes
#pragma unroll
    for (int m = 1; m < 16; m <<= 1)
#pragma unroll
        for (int rg = 0; rg < 4; ++rg)
#pragma unroll
            for (int reg = 0; reg < 4; ++reg)
                px[rg][reg] += __shfl_xor(px[rg][reg], m, 64);
    if (n == 0)
#pragma unroll
        for (int rg = 0; rg < 4; ++rg)
#pragma unroll
            for (int reg = 0; reg < 4; ++reg)
                pxl[wv * 64 + 16 * rg + 4 * qd + reg] = px[rg][reg];
    __syncthreads();  // b3: Bb16, Cb16, pxl, zsh, dl ready

    // ---- scan phase (replicated per wave, lane = chunk row l)
    const int l = lane;
    const float dt = log1pf(expf(dtp[0])) + 0.01f;
    float zA = zsh[l] + conv_b[32];
    float aA = zA + 1.f / (1.f + __expf(-zA));
    float An = -fabsf(aA);
    float lAd = dt * An;
    float fac = (__expf(lAd) - 1.f) / (An + 1e-9f);
    float s = lAd;  // inclusive Kogge-Stone scan over 64 lanes
#pragma unroll
    for (int k = 1; k < 64; k <<= 1) {
        float t = __shfl_up(s, k, 64);
        if (l >= k) s += t;
    }
    const float acs_l = s;
    const float tot = __shfl(s, 63, 64);
    float xq = pxl[0 * 64 + l] + pxl[1 * 64 + l] + pxl[2 * 64 + l] + pxl[3 * 64 + l];
    const float wd = fac * xq;                                // diag weight
    const float wsd = wd * __expf(fmaxf(tot - acs_l, -20.f)); // state weight
    if (wv == 3) {
        Acs_ws[bs * Tn + ci * 64 + l] = acs_l;
        if (l == 0) csum_ws[bs * 64 + ci] = tot;
    }
    if (wv == 1) {  // publish per-row scan values for m-indexed access
        acs_s[l] = acs_l;
        wd_s[l] = wd;
    }

    // ---- sred from wv0's live a0 regs: sred[n] = sum_m a0[m,n]*wsd[m]
    if (wv == 0) {
        float sp = 0.f;
#pragma unroll
        for (int rg = 0; rg < 4; ++rg)
#pragma unroll
            for (int reg = 0; reg < 4; ++reg)
                sp += accA[rg][reg] * __shfl(wsd, 16 * rg + 4 * qd + reg, 64);
        sp += __shfl_xor(sp, 16, 64);
        sp += __shfl_xor(sp, 32, 64);
        if (l < 16) sred_ws[(bs * 64 + ci) * 16 + l] = sp;
    }
    __syncthreads();  // b4: acs_s, wd_s ready

    // ---- Y_diag via Gram MFMA: wave wv owns l-rows [16wv, 16wv+16).
    // G tile: A = C rows (Cb16), B = B0 rows (Bb16), K=16 padded to 32
    // (qd>=2 fragments zero). D[row=4qd+reg][col=n] = G[16wv+4qd+reg][16mt+n].
    const bf16x8 zzv = (bf16x8){0, 0, 0, 0, 0, 0, 0, 0};
    bf16x8 af = (qd < 2) ? *(const bf16x8*)&Cb16[(16 * wv + n) * 16 + qd * 8]
                         : zzv;
    f32x4 g0 = (f32x4){0.f, 0.f, 0.f, 0.f}, g1 = g0, g2 = g0, g3 = g0;
    {
        bf16x8 bf0 = (qd < 2) ? *(const bf16x8*)&Bb16[(n) * 16 + qd * 8] : zzv;
        bf16x8 bf1 = (qd < 2) ? *(const bf16x8*)&Bb16[(16 + n) * 16 + qd * 8] : zzv;
        bf16x8 bf2 = (qd < 2) ? *(const bf16x8*)&Bb16[(32 + n) * 16 + qd * 8] : zzv;
        bf16x8 bf3 = (qd < 2) ? *(const bf16x8*)&Bb16[(48 + n) * 16 + qd * 8] : zzv;
        g0 = __builtin_amdgcn_mfma_f32_16x16x32_bf16(af, bf0, g0, 0, 0, 0);
        g1 = __builtin_amdgcn_mfma_f32_16x16x32_bf16(af, bf1, g1, 0, 0, 0);
        g2 = __builtin_amdgcn_mfma_f32_16x16x32_bf16(af, bf2, g2, 0, 0, 0);
        g3 = __builtin_amdgcn_mfma_f32_16x16x32_bf16(af, bf3, g3, 0, 0, 0);
    }

    // weighting: part[reg] += exp(arg(l,m)) * G * wd[m], m = 16mt+n
    float acsr[4];
#pragma unroll
    for (int reg = 0; reg < 4; ++reg)
        acsr[reg] = acs_s[16 * wv + 4 * qd + reg];
    float part[4] = {0.f, 0.f, 0.f, 0.f};
#pragma unroll
    for (int mt = 0; mt < 4; ++mt) {
        const int m = 16 * mt + n;
        const float am = acs_s[m];
        const float wm = wd_s[m];
        const f32x4 g = (mt == 0) ? g0 : (mt == 1) ? g1 : (mt == 2) ? g2 : g3;
#pragma unroll
        for (int reg = 0; reg < 4; ++reg) {
            const int lr = 16 * wv + 4 * qd + reg;
            float arg = (m <= lr) ? fmaxf(acsr[reg] - am, -20.f) : -20.f;
            part[reg] += __expf(arg) * g[reg] * wm;
        }
    }
    // reduce over the 16 'n' lanes of each qd group
#pragma unroll
    for (int mk = 1; mk < 16; mk <<= 1)
#pragma unroll
        for (int reg = 0; reg < 4; ++reg)
            part[reg] += __shfl_xor(part[reg], mk, 64);
    if (n == 0) {
#pragma unroll
        for (int reg = 0; reg < 4; ++reg) {
            const int lr = 16 * wv + 4 * qd + reg;
            yp_ws[bs * Tn + ci * 64 + lr] = part[reg] + dl[lr];
        }
    }
}

// K2: fused inter-chunk scan + output (r16-validated, bf16 Cm read).
__global__ __launch_bounds__(256) void k_out(
    const unsigned short* __restrict__ Cm_h, const float* __restrict__ Acs_ws,
    const float* __restrict__ sred_ws, const float* __restrict__ csum_ws,
    const float* __restrict__ yp_ws, float* __restrict__ out) {
    const int bs = blockIdx.y;
    const int tid = threadIdx.x;
    const int wv = tid >> 6, l = tid & 63;
    const int ci = blockIdx.x * 4 + wv;
    __shared__ float sn[4][16];
    const int base = bs * Tn + ci * 64;

    // in-block affine scan (validated): lane = chunk id, wave wv handles
    // n = 4*wv .. 4*wv+3.
    const float dexp = __expf(csum_ws[bs * 64 + l]);  // <= 1
#pragma unroll
    for (int j = 0; j < 4; ++j) {
        const int n = 4 * wv + j;
        float s = sred_ws[(bs * 64 + l) * 16 + n];
        float d = dexp;
#pragma unroll
        for (int k = 1; k < 64; k <<= 1) {
            float dp = __shfl_up(d, k, 64);
            float sp = __shfl_up(s, k, 64);
            if (l >= k) {
                s = d * sp + s;  // compose on top of lower segment (old d!)
                d = d * dp;
            }
        }
        float se = __shfl_up(s, 1, 64);
        float sns = (l == 0) ? 0.f : se;
        if ((l >> 2) == blockIdx.x) sn[l & 3][n] = sns;
    }

    const unsigned short* crow = &Cm_h[((bs * 64 + ci) * 64 + l) * 16];
    uint4 ua = *(const uint4*)crow;        // bf16 c0..c7
    uint4 ub = *(const uint4*)(crow + 8);  // bf16 c8..c15
    float yp = yp_ws[base + l];
    float acl = Acs_ws[base + l];
    __syncthreads();

    const float* s = sn[wv];
    float go = bflo(ua.x) * s[0]  + bfhi(ua.x) * s[1] +
               bflo(ua.y) * s[2]  + bfhi(ua.y) * s[3] +
               bflo(ua.z) * s[4]  + bfhi(ua.z) * s[5] +
               bflo(ua.w) * s[6]  + bfhi(ua.w) * s[7] +
               bflo(ub.x) * s[8]  + bfhi(ub.x) * s[9] +
               bflo(ub.y) * s[10] + bfhi(ub.y) * s[11] +
               bflo(ub.z) * s[12] + bfhi(ub.z) * s[13] +
               bflo(ub.w) * s[14] + bfhi(ub.w) * s[15];
    out[(ci * 64 + l) * 64 + bs] = yp + __expf(acl) * go;
}

extern "C" void kernel_launch(void* const* d_in, const int* in_sizes, int n_in,
                              void* d_out, int out_size, void* d_ws,
                              size_t ws_size, hipStream_t stream) {
    const float* x = (const float*)d_in[0];
    const float* conv_w = (const float*)d_in[1];
    const float* conv_b = (const float*)d_in[2];
    const float* pass_w = (const float*)d_in[3];
    const float* pass_b = (const float*)d_in[4];
    const float* red_w = (const float*)d_in[5];
    const float* red_b = (const float*)d_in[6];
    const float* dtp = (const float*)d_in[7];
    float* out = (float*)d_out;
    float* W = (float*)d_ws;
    (void)in_sizes; (void)n_in; (void)out_size; (void)ws_size;

    unsigned short* Cm_h = (unsigned short*)(W + OFF_CM);
    float* yp_ws = W + OFF_DL;
    float* Acs_ws = W + OFF_ACS;
    float* sred_ws = W + OFF_SRED;
    float* csum_ws = W + OFF_CSUM;
    unsigned short* wbh = (unsigned short*)(W + OFF_WBH);
    unsigned short* wbl = (unsigned short*)(W + OFF_WBL);

    k_prep<<<dim3((Kn * CHP * Fn + 255) / 256), dim3(256), 0, stream>>>(
        conv_w, pass_w, wbh, wbl);
    k_fwd<<<dim3(NCn * BSn), dim3(256), 0, stream>>>(
        x, wbh, wbl, conv_b, pass_b, red_w, red_b, dtp,
        Cm_h, Acs_ws, yp_ws, sred_ws, csum_ws);
    k_out<<<dim3(NCn / 4, BSn), dim3(256), 0, stream>>>(
        Cm_h, Acs_ws, sred_ws, csum_ws, yp_ws, out);
}